// Round 5
// baseline (1418.946 us; speedup 1.0000x reference)
//
#include <hip/hip_runtime.h>

#define T_TOK 16384
#define HDIM  1024
#define IDIM  2048
#define NEXP  8
#define CNT_STRIDE 32     // pad each expert counter to its own 128B cache line
#define TOK_PER_BLK 32    // tokens handled per 256-thread router block
#define MAX_RTILES 144    // max padded 256-row tiles over all routed experts

typedef __attribute__((ext_vector_type(8))) short bf16x8;
typedef __attribute__((ext_vector_type(4))) float f32x4;
typedef unsigned short u16;
typedef unsigned int u32;

typedef __attribute__((address_space(1))) const unsigned int gas_u32;
typedef __attribute__((address_space(3))) unsigned int las_u32;

// async global->LDS, 16B per lane; LDS dest = base + lane*16 (wave-uniform base)
__device__ __forceinline__ void gl16(const void* g, void* l) {
  __builtin_amdgcn_global_load_lds((gas_u32*)g, (las_u32*)l, 16, 0, 0);
}

__device__ __forceinline__ u16 f2bf(float f) {
  union { float f; u32 i; } v; v.f = f;
  u32 r = v.i + 0x7FFF + ((v.i >> 16) & 1);  // RNE
  return (u16)(r >> 16);
}
__device__ __forceinline__ u32 pack2(float a, float b) {
  return (u32)f2bf(a) | ((u32)f2bf(b) << 16);
}

// ---------------- f32 -> bf16 elementwise convert ---------------------------
__global__ __launch_bounds__(256) void cvt_kernel(
    const float* __restrict__ s, u16* __restrict__ d, int n)
{
  int i = (blockIdx.x * 256 + threadIdx.x) * 4;
  if (i < n) {
    f32x4 v = *(const f32x4*)(s + i);
    uint2 o; o.x = pack2(v[0], v[1]); o.y = pack2(v[2], v[3]);
    *(uint2*)(d + i) = o;
  }
}

// ---- f32 Wg/Wu -> bf16 interleaved [Wg;Wu] rows (16-row blocks alternate) --
__global__ __launch_bounds__(256) void cvt_gu_kernel(
    const float* __restrict__ Wg, const float* __restrict__ Wu,
    u16* __restrict__ d, int nrows)   // nrows = E * 2 * IDIM
{
  int i = (blockIdx.x * 256 + threadIdx.x) * 4;
  if (i >= nrows * 1024) return;
  int r = i >> 10, c = i & 1023;
  int eb = r >> 12;            // expert (4096 interleaved rows each)
  int rr = r & 4095;
  int sub = rr & 31, b = rr >> 5;
  const float* s = (sub < 16 ? Wg : Wu) +
                   (((size_t)(eb * IDIM + b * 16 + (sub & 15))) << 10) + c;
  f32x4 v = *(const f32x4*)s;
  uint2 o; o.x = pack2(v[0], v[1]); o.y = pack2(v[2], v[3]);
  *(uint2*)(d + i) = o;
}

__global__ void init_counts(int* counts) {
  counts[threadIdx.x] = 0;  // launched with NEXP*CNT_STRIDE threads
}

// ---------------- router: f64 logits, top2 on logits ------------------------
__global__ __launch_bounds__(256) void router_kernel(
    const float* __restrict__ x, const float* __restrict__ Wr,
    const float* __restrict__ rb, float* __restrict__ cw,
    int* __restrict__ counts, int* __restrict__ lists)
{
  __shared__ __align__(16) float sWr[NEXP * HDIM];   // 32 KB
  __shared__ int pickE[2 * TOK_PER_BLK];
  __shared__ int pickT[2 * TOK_PER_BLK];

  const int tid = threadIdx.x;
  const int lane = tid & 63;
  const int wv = tid >> 6;

  for (int i = tid; i < NEXP * HDIM / 4; i += 256)
    ((f32x4*)sWr)[i] = ((const f32x4*)Wr)[i];

  float rbl[NEXP];
  #pragma unroll
  for (int e = 0; e < NEXP; ++e) rbl[e] = rb[e];

  __syncthreads();

  const int t_base = blockIdx.x * TOK_PER_BLK + wv * (TOK_PER_BLK / 4);
  for (int j = 0; j < TOK_PER_BLK / 4; ++j) {
    const int t = t_base + j;
    const float* xrow = x + (size_t)t * HDIM;
    f32x4 xv[4];
    #pragma unroll
    for (int c = 0; c < 4; ++c) xv[c] = *(const f32x4*)(xrow + c * 256 + lane * 4);

    double acc[NEXP];
    #pragma unroll
    for (int e = 0; e < NEXP; ++e) {
      const float* wr = sWr + e * HDIM;
      double a = 0.0;
      #pragma unroll
      for (int c = 0; c < 4; ++c) {
        f32x4 w4 = *(const f32x4*)(wr + c * 256 + lane * 4);
        a += (double)xv[c][0] * (double)w4[0];
        a += (double)xv[c][1] * (double)w4[1];
        a += (double)xv[c][2] * (double)w4[2];
        a += (double)xv[c][3] * (double)w4[3];
      }
      acc[e] = a;
    }
    #pragma unroll
    for (int e = 0; e < NEXP; ++e) {
      double a = acc[e];
      a += __shfl_xor(a, 1, 64);
      a += __shfl_xor(a, 2, 64);
      a += __shfl_xor(a, 4, 64);
      acc[e] = a;
    }
    double s0 = (lane & 1) ? acc[1] : acc[0];
    double s1 = (lane & 1) ? acc[3] : acc[2];
    double s2 = (lane & 1) ? acc[5] : acc[4];
    double s3 = (lane & 1) ? acc[7] : acc[6];
    double u0 = (lane & 2) ? s1 : s0;
    double u1 = (lane & 2) ? s3 : s2;
    double v  = (lane & 4) ? u1 : u0;
    v += __shfl_xor(v, 8, 64);
    v += __shfl_xor(v, 16, 64);
    v += __shfl_xor(v, 32, 64);
    double l[NEXP];
    #pragma unroll
    for (int e = 0; e < NEXP; ++e) l[e] = __shfl(v, e, 64) + (double)rbl[e];

    if (lane == 0) {
      int i1 = 0;
      #pragma unroll
      for (int e = 1; e < NEXP; ++e) if (l[e] > l[i1]) i1 = e;
      int i2 = -1;
      #pragma unroll
      for (int e = 0; e < NEXP; ++e) {
        if (e == i1) continue;
        if (i2 < 0 || l[e] > l[i2]) i2 = e;
      }
      float p1 = (float)(1.0 / (1.0 + exp(-l[i1])));
      float p2 = (float)(1.0 / (1.0 + exp(-l[i2])));
      cw[(size_t)t * NEXP + i1] = p1;
      cw[(size_t)t * NEXP + i2] = p2;
      int slot = (wv * (TOK_PER_BLK / 4) + j) * 2;
      pickE[slot] = i1; pickE[slot + 1] = i2;
      pickT[slot] = t;  pickT[slot + 1] = t;
    }
  }
  __syncthreads();

  const int myE = pickE[lane];
  const int myT = pickT[lane];
  #pragma unroll
  for (int ei = 0; ei < 2; ++ei) {
    int e = wv + ei * 4;
    unsigned long long b = __ballot(myE == e);
    int cnt = __popcll(b);
    int base = 0;
    if (lane == 0) base = atomicAdd(&counts[e * CNT_STRIDE], cnt);
    base = __shfl(base, 0, 64);
    if (myE == e)
      lists[(size_t)e * T_TOK + base + __popcll(b & ((1ull << lane) - 1))] = myT;
  }
}

// ---------------- build 256-row tile descriptors over all routed experts ----
__global__ void build_tiles(const int* __restrict__ counts,
                            int* __restrict__ td_e, int* __restrict__ td_r0,
                            int* __restrict__ ntiles)
{
  if (threadIdx.x == 0) {
    int n = 0;
    for (int e = 0; e < NEXP; ++e) {
      int c = counts[e * CNT_STRIDE];
      for (int r = 0; r < c; r += 256) { td_e[n] = e; td_r0[n] = r; ++n; }
    }
    *ntiles = n;
  }
}

// ===================== 8-phase 256x256 pipelined GEMM cores ==================
// BM=BN=256, BK=64, 512 thr = 8 waves (2M x 4N), per-wave 128x64.
// LDS per matrix: [2 dbuf][2 ks][256 rows][32 cols] bf16 = 64 KB (128 KB tot).
// Per K-tile: 4 phases {ds_read subset | stage 1 group -> bar -> lgkm0 ->
// 16 MFMA -> bar}, staging grouped by K-half, vmcnt(4) at phases 1 & 3 only.
// Swizzle: read slot = quad ^ ((l15>>1)&3); source chunk = (l&3)^((l>>3)&3).

__device__ __forceinline__ void ld_a4(const u16* baseA, int arow, bf16x8 (&af)[4]) {
  #pragma unroll
  for (int i = 0; i < 4; ++i) af[i] = *(const bf16x8*)(baseA + arow + i * 512);
}
__device__ __forceinline__ void ld_b4(const u16* baseB, int brow, bf16x8 (&bf)[4]) {
  #pragma unroll
  for (int n = 0; n < 4; ++n) bf[n] = *(const bf16x8*)(baseB + brow + n * 512);
}
__device__ __forceinline__ void mfma16q(bf16x8 (&af)[4], bf16x8 (&bf)[4],
                                        f32x4 (&aq)[4][4]) {
  __builtin_amdgcn_s_setprio(1);
  #pragma unroll
  for (int n = 0; n < 4; ++n) {
    #pragma unroll
    for (int i = 0; i < 4; ++i)
      aq[i][n] = __builtin_amdgcn_mfma_f32_16x16x32_bf16(af[i], bf[n], aq[i][n], 0, 0, 0);
  }
  __builtin_amdgcn_s_setprio(0);
}
#define PH_OPEN()  do { __builtin_amdgcn_s_barrier(); \
    asm volatile("s_waitcnt lgkmcnt(0)" ::: "memory"); \
    __builtin_amdgcn_sched_barrier(0); } while (0)
#define PH_CLOSE() __builtin_amdgcn_s_barrier()
#define VMW(n) asm volatile("s_waitcnt vmcnt(" #n ")" ::: "memory")

// ---------------- pass A: h = silu(gate)*up via interleaved [Wg;Wu] ---------
template<bool FUSED>
__global__ __launch_bounds__(512, 2) void gateup256(
    const u16* __restrict__ xb, const u16* __restrict__ Wgu,
    const int* __restrict__ lists, const int* __restrict__ counts,
    const int* __restrict__ td_e, const int* __restrict__ td_r0,
    const int* __restrict__ ntiles,
    u16* __restrict__ hbuf, int t0c0)
{
  __shared__ __align__(16) u16 sA[2 * 2 * 256 * 32];   // 64 KB
  __shared__ __align__(16) u16 sB[2 * 2 * 256 * 32];   // 64 KB

  int r0, cnt; const int* list = nullptr;
  const u16* W;
  if (FUSED) {
    int ty = t0c0 + blockIdx.y;
    if (ty >= *ntiles) return;
    int e = td_e[ty]; r0 = td_r0[ty]; cnt = counts[e * CNT_STRIDE];
    list = lists + (size_t)e * T_TOK;
    W = Wgu + (size_t)e * 2 * IDIM * HDIM;
  } else {
    r0 = t0c0 + blockIdx.y * 256; cnt = T_TOK;
    W = Wgu;
  }
  const int n0 = blockIdx.x * 256;   // interleaved-col tile base (0..4095)

  const int tid = threadIdx.x, lane = tid & 63, w = tid >> 6;
  const int wm = w >> 2, wn = w & 3;
  const int quad = lane >> 4, l15 = lane & 15;

  // staging geometry: wave w covers rows [w*32, w*32+32); gl16 i covers
  // rows +i*16..+i*16+15; lane l -> row +(l>>2), phys slot l&3;
  // source chunk q = (l&3)^((l>>3)&3)  (inverse of read swizzle)
  const int srow = (lane >> 2);                  // 0..15 within gl16 block
  const int q = (lane & 3) ^ ((lane >> 3) & 3);  // 16B chunk within 32 cols

  const u16 *pA[2], *pB[2];
  u16 *dA[2], *dB[2];
  #pragma unroll
  for (int i = 0; i < 2; ++i) {
    int row = w * 32 + i * 16 + srow;
    int tok;
    if (FUSED) { int gi = r0 + row; tok = (gi < cnt) ? list[gi] : 0; }
    else tok = r0 + row;
    pA[i] = xb + (size_t)tok * HDIM + q * 8;
    pB[i] = W + (size_t)(n0 + row) * HDIM + q * 8;
    dA[i] = sA + (w * 32 + i * 16) * 32;
    dB[i] = sB + (w * 32 + i * 16) * 32;
  }

  // frag-read addressing (u16): swizzled slot constant per lane
  const int swz = (quad ^ ((l15 >> 1) & 3)) * 8;
  const int arow = (wm * 128 + l15) * 32 + swz;
  const int brow = (wn * 64 + l15) * 32 + swz;

  f32x4 accL[4][4] = {};   // mt 0..3
  f32x4 accH[4][4] = {};   // mt 4..7

  auto STAGE_A = [&](int t, int b, int h) {
    #pragma unroll
    for (int i = 0; i < 2; ++i)
      gl16(pA[i] + (size_t)t * 64 + h * 32, dA[i] + b * 16384 + h * 8192);
  };
  auto STAGE_B = [&](int t, int b, int h) {
    #pragma unroll
    for (int i = 0; i < 2; ++i)
      gl16(pB[i] + (size_t)t * 64 + h * 32, dB[i] + b * 16384 + h * 8192);
  };

  const int NT = HDIM / 64;  // 16
  // prologue: tile 0 -> buf 0; ks0 landed, ks1 in flight (4 outstanding)
  STAGE_A(0, 0, 0); STAGE_B(0, 0, 0);
  STAGE_A(0, 0, 1); STAGE_B(0, 0, 1);
  VMW(4);
  __builtin_amdgcn_s_barrier();

  for (int t = 0; t < NT; ++t) {
    const int cur = t & 1, nb = cur ^ 1;
    const int tn = (t + 1 < NT) ? t + 1 : t;   // tail: restage valid addrs
    const u16* cA = sA + cur * 16384;
    const u16* cB = sB + cur * 16384;
    bf16x8 af[4], bf[4];
    // phase 0: ks0, mt0-3 (+B ks0); stage next A-ks0
    ld_a4(cA, arow, af); ld_b4(cB, brow, bf);
    STAGE_A(tn, nb, 0);
    PH_OPEN(); mfma16q(af, bf, accL); PH_CLOSE();
    // phase 1: ks0, mt4-7; stage next B-ks0; drain cur ks1
    ld_a4(cA + 2048, arow, af);
    STAGE_B(tn, nb, 0);
    PH_OPEN(); mfma16q(af, bf, accH); VMW(4); PH_CLOSE();
    // phase 2: ks1, mt0-3 (+B ks1); stage next A-ks1
    ld_a4(cA + 8192, arow, af); ld_b4(cB + 8192, brow, bf);
    STAGE_A(tn, nb, 1);
    PH_OPEN(); mfma16q(af, bf, accL); PH_CLOSE();
    // phase 3: ks1, mt4-7; stage next B-ks1; drain next ks0
    ld_a4(cA + 8192 + 2048, arow, af);
    STAGE_B(tn, nb, 1);
    PH_OPEN(); mfma16q(af, bf, accH); VMW(4); PH_CLOSE();
  }
  VMW(0);

  // epilogue: even/odd 16-col frags are (gate, up) of the same h columns
  const size_t hrb = (size_t)blockIdx.y * 256;
  #pragma unroll
  for (int mt = 0; mt < 8; ++mt) {
    #pragma unroll
    for (int i = 0; i < 4; ++i) {
      int rl = wm * 128 + mt * 16 + quad * 4 + i;
      u16* orow = hbuf + (hrb + rl) * IDIM + (n0 >> 1) + wn * 32 + l15;
      #pragma unroll
      for (int j = 0; j < 2; ++j) {
        float g = (mt < 4) ? accL[mt][2 * j][i]     : accH[mt - 4][2 * j][i];
        float u = (mt < 4) ? accL[mt][2 * j + 1][i] : accH[mt - 4][2 * j + 1][i];
        float h = (g / (1.f + __expf(-g))) * u;
        orow[j * 16] = f2bf(h);
      }
    }
  }
}

// ---------------- pass B: out[tok] (+)= cw * (h Wd^T) -----------------------
template<bool FUSED>
__global__ __launch_bounds__(512, 2) void down256(
    const u16* __restrict__ hbuf, const u16* __restrict__ Wd_b,
    const int* __restrict__ lists, const int* __restrict__ counts,
    const int* __restrict__ td_e, const int* __restrict__ td_r0,
    const int* __restrict__ ntiles,
    const float* __restrict__ cw, float* __restrict__ out, int t0c0)
{
  __shared__ __align__(16) u16 sA[2 * 2 * 256 * 32];
  __shared__ __align__(16) u16 sB[2 * 2 * 256 * 32];

  int e = 0, r0, cnt; const int* list = nullptr;
  const u16* Wd;
  if (FUSED) {
    int ty = t0c0 + blockIdx.y;
    if (ty >= *ntiles) return;
    e = td_e[ty]; r0 = td_r0[ty]; cnt = counts[e * CNT_STRIDE];
    list = lists + (size_t)e * T_TOK;
    Wd = Wd_b + (size_t)e * IDIM * HDIM;
  } else {
    r0 = t0c0 + blockIdx.y * 256; cnt = T_TOK;
    Wd = Wd_b;
  }
  const int n0 = blockIdx.x * 256;   // 0..768

  const int tid = threadIdx.x, lane = tid & 63, w = tid >> 6;
  const int wm = w >> 2, wn = w & 3;
  const int quad = lane >> 4, l15 = lane & 15;

  const int srow = (lane >> 2);
  const int q = (lane & 3) ^ ((lane >> 3) & 3);

  const u16 *pA[2], *pB[2];
  u16 *dA[2], *dB[2];
  #pragma unroll
  for (int i = 0; i < 2; ++i) {
    int row = w * 32 + i * 16 + srow;
    pA[i] = hbuf + (size_t)(blockIdx.y * 256 + row) * IDIM + q * 8;
    pB[i] = Wd + (size_t)(n0 + row) * IDIM + q * 8;
    dA[i] = sA + (w * 32 + i * 16) * 32;
    dB[i] = sB + (w * 32 + i * 16) * 32;
  }

  const int swz = (quad ^ ((l15 >> 1) & 3)) * 8;
  const int arow = (wm * 128 + l15) * 32 + swz;
  const int brow = (wn * 64 + l15) * 32 + swz;

  f32x4 accL[4][4] = {};
  f32x4 accH[4][4] = {};

  auto STAGE_A = [&](int t, int b, int h) {
    #pragma unroll
    for (int i = 0; i < 2; ++i)
      gl16(pA[i] + (size_t)t * 64 + h * 32, dA[i] + b * 16384 + h * 8192);
  };
  auto STAGE_B = [&](int t, int b, int h) {
    #pragma unroll
    for (int i = 0; i < 2; ++i)
      gl16(pB[i] + (size_t)t * 64 + h * 32, dB[i] + b * 16384 + h * 8192);
  };

  const int NT = IDIM / 64;  // 32
  STAGE_A(0, 0, 0); STAGE_B(0, 0, 0);
  STAGE_A(0, 0, 1); STAGE_B(0, 0, 1);
  VMW(4);
  __builtin_amdgcn_s_barrier();

  for (int t = 0; t < NT; ++t) {
    const int cur = t & 1, nb = cur ^ 1;
    const int tn = (t + 1 < NT) ? t + 1 : t;
    const u16* cA = sA + cur * 16384;
    const u16* cB = sB + cur * 16384;
    bf16x8 af[4], bf[4];
    ld_a4(cA, arow, af); ld_b4(cB, brow, bf);
    STAGE_A(tn, nb, 0);
    PH_OPEN(); mfma16q(af, bf, accL); PH_CLOSE();
    ld_a4(cA + 2048, arow, af);
    STAGE_B(tn, nb, 0);
    PH_OPEN(); mfma16q(af, bf, accH); VMW(4); PH_CLOSE();
    ld_a4(cA + 8192, arow, af); ld_b4(cB + 8192, brow, bf);
    STAGE_A(tn, nb, 1);
    PH_OPEN(); mfma16q(af, bf, accL); PH_CLOSE();
    ld_a4(cA + 8192 + 2048, arow, af);
    STAGE_B(tn, nb, 1);
    PH_OPEN(); mfma16q(af, bf, accH); VMW(4); PH_CLOSE();
  }
  VMW(0);

  #pragma unroll
  for (int mt = 0; mt < 8; ++mt) {
    #pragma unroll
    for (int i = 0; i < 4; ++i) {
      int rl = wm * 128 + mt * 16 + quad * 4 + i;
      f32x4* accp = (mt < 4) ? &accL[mt][0] : &accH[mt - 4][0];
      if (FUSED) {
        if (r0 + rl < cnt) {
          int token = list[r0 + rl];
          float s = cw[(size_t)token * NEXP + e];
          float* orow = out + (size_t)token * HDIM + n0 + wn * 64 + l15;
          #pragma unroll
          for (int nt = 0; nt < 4; ++nt)
            atomicAdd(&orow[nt * 16], s * accp[nt][i]);
        }
      } else {
        int token = r0 + rl;
        float* orow = out + (size_t)token * HDIM + n0 + wn * 64 + l15;
        #pragma unroll
        for (int nt = 0; nt < 4; ++nt)
          orow[nt * 16] = accp[nt][i];
      }
    }
  }
}

// ============== fallback (small-ws) f32-source 128^2 kernels ================
template<int SRC>
__global__ __launch_bounds__(256, 2) void moe_gateup_k(
    const u16* __restrict__ xb, const float* __restrict__ xf,
    const u16* __restrict__ Wg_b, const u16* __restrict__ Wu_b,
    const float* __restrict__ Wg_f, const float* __restrict__ Wu_f,
    const int* __restrict__ list, const int* __restrict__ count_ptr,
    u16* __restrict__ hbuf, int c0)
{
  __shared__ __align__(16) u16 sA[128 * 32];
  __shared__ __align__(16) u16 sG[128 * 32];
  __shared__ __align__(16) u16 sU[128 * 32];

  const int cnt = count_ptr ? *count_ptr : T_TOK;
  const int remain = cnt - c0;
  const int m0 = blockIdx.y * 128;
  if (m0 >= remain) return;
  const int n0 = blockIdx.x * 128;

  const int tid = threadIdx.x, lane = tid & 63, w = tid >> 6;
  const int wm = w & 1, wn = w >> 1;
  const int quad = lane >> 4, l15 = lane & 15;

  const int ar = lane >> 3, ac = lane & 7;

  const float *fa[4], *fg[4], *fu[4];
  int frow[4];
  #pragma unroll
  for (int p = 0; p < 4; ++p) {
    int row = w * 32 + p * 8 + ar;
    frow[p] = row;
    int gi = c0 + m0 + row;
    int tok = (gi < cnt) ? (list ? list[gi] : gi) : 0;
    fa[p] = xf + (size_t)tok * HDIM + ac * 4;
    fg[p] = Wg_f + (size_t)(n0 + row) * HDIM + ac * 4;
    fu[p] = Wu_f + (size_t)(n0 + row) * HDIM + ac * 4;
  }

  const u16* fA = sA + (wm * 64 + l15) * 32 + quad * 8;
  const u16* fG = sG + (wn * 64 + l15) * 32 + quad * 8;
  const u16* fU = sU + (wn * 64 + l15) * 32 + quad * 8;

  f32x4 accG[4][4] = {};
  f32x4 accU[4][4] = {};

  for (int kt = 0; kt < HDIM / 32; ++kt) {
    #pragma unroll
    for (int p = 0; p < 4; ++p) {
      f32x4 va = *(const f32x4*)(fa[p] + kt * 32);
      f32x4 vg = *(const f32x4*)(fg[p] + kt * 32);
      f32x4 vu = *(const f32x4*)(fu[p] + kt * 32);
      uint2 oa; oa.x = pack2(va[0], va[1]); oa.y = pack2(va[2], va[3]);
      uint2 og; og.x = pack2(vg[0], vg[1]); og.y = pack2(vg[2], vg[3]);
      uint2 ou; ou.x = pack2(vu[0], vu[1]); ou.y = pack2(vu[2], vu[3]);
      *(uint2*)(sA + frow[p] * 32 + ac * 4) = oa;
      *(uint2*)(sG + frow[p] * 32 + ac * 4) = og;
      *(uint2*)(sU + frow[p] * 32 + ac * 4) = ou;
    }
    __syncthreads();
    bf16x8 a[4];
    #pragma unroll
    for (int mt = 0; mt < 4; ++mt) a[mt] = *(const bf16x8*)(fA + mt * 16 * 32);
    #pragma unroll
    for (int nt = 0; nt < 4; ++nt) {
      bf16x8 bg = *(const bf16x8*)(fG + nt * 16 * 32);
      bf16x8 bu = *(const bf16x8*)(fU + nt * 16 * 32);
      #pragma unroll
      for (int mt = 0; mt < 4; ++mt) {
        accG[mt][nt] = __builtin_amdgcn_mfma_f32_16x16x32_bf16(a[mt], bg, accG[mt][nt], 0, 0, 0);
        accU[mt][nt] = __builtin_amdgcn_mfma_f32_16x16x32_bf16(a[mt], bu, accU[mt][nt], 0, 0, 0);
      }
    }
    __syncthreads();
  }

  #pragma unroll
  for (int mt = 0; mt < 4; ++mt) {
    #pragma unroll
    for (int i = 0; i < 4; ++i) {
      int row = m0 + wm * 64 + mt * 16 + quad * 4 + i;
      if (row < remain) {
        u16* orow = hbuf + (size_t)row * IDIM + n0 + wn * 64 + l15;
        #pragma unroll
        for (int nt = 0; nt < 4; ++nt) {
          float g = accG[mt][nt][i], u = accU[mt][nt][i];
          float h = (g / (1.f + __expf(-g))) * u;
          orow[nt * 16] = f2bf(h);
        }
      }
    }
  }
  (void)xb; (void)Wg_b; (void)Wu_b;
}

template<int SRC>
__global__ __launch_bounds__(256, 2) void moe_down_k(
    const u16* __restrict__ hbuf,
    const u16* __restrict__ Wd_b, const float* __restrict__ Wd_f,
    const int* __restrict__ list, const int* __restrict__ count_ptr,
    const float* __restrict__ cw, int expert, float* __restrict__ out, int c0)
{
  __shared__ __align__(16) u16 sA[128 * 32];
  __shared__ __align__(16) u16 sB[128 * 32];

  const int cnt = count_ptr ? *count_ptr : T_TOK;
  const int remain = cnt - c0;
  const int m0 = blockIdx.y * 128;
  if (m0 >= remain) return;
  const int n0 = blockIdx.x * 128;

  const int tid = threadIdx.x, lane = tid & 63, w = tid >> 6;
  const int wm = w & 1, wn = w >> 1;
  const int quad = lane >> 4, l15 = lane & 15;

  const int srow0 = w * 32 + (lane >> 2);
  const int srow1 = srow0 + 16;
  const int kch = (lane & 3) * 8;
  const int ar = lane >> 3, ac = lane & 7;

  const u16* pa0 = hbuf + (size_t)(m0 + srow0) * IDIM + kch;
  const u16* pa1 = hbuf + (size_t)(m0 + srow1) * IDIM + kch;
  const float* fb[4];
  int frow[4];
  #pragma unroll
  for (int p = 0; p < 4; ++p) {
    int row = w * 32 + p * 8 + ar;
    frow[p] = row;
    fb[p] = Wd_f + (size_t)(n0 + row) * IDIM + ac * 4;
  }

  const u16* fA = sA + (wm * 64 + l15) * 32 + quad * 8;
  const u16* fB = sB + (wn * 64 + l15) * 32 + quad * 8;

  f32x4 acc[4][4] = {};

  for (int kt = 0; kt < IDIM / 32; ++kt) {
    gl16(pa0 + kt * 32, sA + w * 1024);
    gl16(pa1 + kt * 32, sA + w * 1024 + 512);
    #pragma unroll
    for (int p = 0; p < 4; ++p) {
      f32x4 v = *(const f32x4*)(fb[p] + kt * 32);
      uint2 o; o.x = pack2(v[0], v[1]); o.y = pack2(v[2], v[3]);
      *(uint2*)(sB + frow[p] * 32 + ac * 4) = o;
    }
    __syncthreads();
    bf16x8 a[4];
    #pragma unroll
    for (int mt = 0; mt < 4; ++mt) a[mt] = *(const bf16x8*)(fA + mt * 16 * 32);
    #pragma unroll
    for (int nt = 0; nt < 4; ++nt) {
      bf16x8 b = *(const bf16x8*)(fB + nt * 16 * 32);
      #pragma unroll
      for (int mt = 0; mt < 4; ++mt)
        acc[mt][nt] = __builtin_amdgcn_mfma_f32_16x16x32_bf16(a[mt], b, acc[mt][nt], 0, 0, 0);
    }
    __syncthreads();
  }

  #pragma unroll
  for (int mt = 0; mt < 4; ++mt) {
    #pragma unroll
    for (int i = 0; i < 4; ++i) {
      int rl = m0 + wm * 64 + mt * 16 + quad * 4 + i;
      if (rl < remain) {
        int token = list ? list[c0 + rl] : (c0 + rl);
        float s = (expert >= 0) ? cw[(size_t)token * NEXP + expert] : 1.f;
        float* orow = out + (size_t)token * HDIM + n0 + wn * 64 + l15;
        #pragma unroll
        for (int nt = 0; nt < 4; ++nt) {
          float v = s * acc[mt][nt][i];
          if (expert >= 0) v += orow[nt * 16];
          orow[nt * 16] = v;
        }
      }
    }
  }
  (void)Wd_b;
}

extern "C" void kernel_launch(void* const* d_in, const int* in_sizes, int n_in,
                              void* d_out, int out_size, void* d_ws, size_t ws_size,
                              hipStream_t stream) {
  (void)in_sizes; (void)n_in; (void)out_size;
  const float* x    = (const float*)d_in[0];
  const float* Wg_s = (const float*)d_in[1];
  const float* Wu_s = (const float*)d_in[2];
  const float* Wd_s = (const float*)d_in[3];
  const float* Wg   = (const float*)d_in[4];
  const float* Wu   = (const float*)d_in[5];
  const float* Wd   = (const float*)d_in[6];
  const float* Wr   = (const float*)d_in[7];
  const float* rb   = (const float*)d_in[8];
  float* out = (float*)d_out;

  char* ws = (char*)d_ws;
  size_t off = 1024;               // counts: NEXP * CNT_STRIDE ints = 1 KB
  int* counts = (int*)ws;
  int* lists = (int*)(ws + off);  off += (size_t)NEXP * T_TOK * 4;
  float* cw = (float*)(ws + off); off += (size_t)T_TOK * NEXP * 4;
  int* td = (int*)(ws + off);     off += 2304;
  int* td_e = td;
  int* td_r0 = td + MAX_RTILES;
  int* ntiles = td + 2 * MAX_RTILES;

  const size_t WSH = (size_t)IDIM * HDIM;
  const size_t xc_elems = (size_t)T_TOK * HDIM;
  const size_t wc_elems = 3 * WSH + 3 * NEXP * WSH;   // 27*WSH
  const size_t fast_need = off + (xc_elems + wc_elems) * 2 + (size_t)2048 * IDIM * 2;
  const bool fast = ws_size >= fast_need;

  u16* xc = (u16*)(ws + off);
  u16* wgus_c = xc + (fast ? xc_elems : 0);   // shared interleaved [Wg;Wu]: 2*WSH
  u16* wds_c  = wgus_c + 2 * WSH;             // shared Wd: WSH
  u16* wgu_c  = wds_c + WSH;                  // routed interleaved: 16*WSH
  u16* wd_c   = wgu_c + 16 * WSH;             // routed Wd: 8*WSH

  size_t hoff = off + (fast ? (xc_elems + wc_elems) * 2 : 0);
  u16* hbuf = (u16*)(ws + hoff);

  size_t avail = (ws_size > hoff) ? (ws_size - hoff) : 0;
  long long capll = (long long)(avail / ((size_t)IDIM * 2));
  int cap = (capll > T_TOK) ? T_TOK : (int)capll;
  cap &= ~255;
  if (cap < 256) cap = 256;
  int nchunks = (T_TOK + cap - 1) / cap;

  init_counts<<<1, NEXP * CNT_STRIDE, 0, stream>>>(counts);
  if (fast) {
    auto cv = [&](const float* s, u16* d, size_t n) {
      int blocks = (int)((n / 4 + 255) / 256);
      cvt_kernel<<<blocks, 256, 0, stream>>>(s, d, (int)n);
    };
    cv(x, xc, xc_elems);
    cv(Wd_s, wds_c, WSH);
    cv(Wd, wd_c, NEXP * WSH);
    {
      int nrows = 2 * IDIM;  // shared
      int blocks = (nrows * 1024 / 4 + 255) / 256;
      cvt_gu_kernel<<<blocks, 256, 0, stream>>>(Wg_s, Wu_s, wgus_c, nrows);
      nrows = NEXP * 2 * IDIM;
      blocks = (nrows * 1024 / 4 + 255) / 256;
      cvt_gu_kernel<<<blocks, 256, 0, stream>>>(Wg, Wu, wgu_c, nrows);
    }
  }
  router_kernel<<<T_TOK / TOK_PER_BLK, 256, 0, stream>>>(x, Wr, rb, cw, counts, lists);

  if (fast) {
    // shared expert: overwrite-store covers every output element
    for (int c = 0; c < nchunks; ++c) {
      int c0 = c * cap;
      int rows = (T_TOK - c0 < cap) ? (T_TOK - c0) : cap;
      dim3 g1(2 * IDIM / 256, rows / 256), g2(HDIM / 256, rows / 256);
      gateup256<false><<<g1, 512, 0, stream>>>(xc, wgus_c, nullptr, nullptr,
                                               nullptr, nullptr, nullptr, hbuf, c0);
      down256<false><<<g2, 512, 0, stream>>>(hbuf, wds_c, nullptr, nullptr,
                                             nullptr, nullptr, nullptr, nullptr, out, c0);
    }
    // routed experts fused: 256-row tiles over all experts, atomic combine
    build_tiles<<<1, 64, 0, stream>>>(counts, td_e, td_r0, ntiles);
    int tpc = cap / 256;
    for (int t0 = 0; t0 < MAX_RTILES; t0 += tpc) {
      int yt = (MAX_RTILES - t0 < tpc) ? (MAX_RTILES - t0) : tpc;
      gateup256<true><<<dim3(2 * IDIM / 256, yt), 512, 0, stream>>>(
          xc, wgu_c, lists, counts, td_e, td_r0, ntiles, hbuf, t0);
      down256<true><<<dim3(HDIM / 256, yt), 512, 0, stream>>>(
          hbuf, wd_c, lists, counts, td_e, td_r0, ntiles, cw, out, t0);
    }
  } else {
    // fallback: f32-source 128^2 path, serialized per-expert RMW
    dim3 blk(256);
    dim3 gA(IDIM / 128, cap / 128);
    dim3 gB(HDIM / 128, cap / 128);
    for (int c = 0; c < nchunks; ++c) {
      int c0 = c * cap;
      moe_gateup_k<1><<<gA, blk, 0, stream>>>(nullptr, x, nullptr, nullptr, Wg_s, Wu_s,
                                              nullptr, nullptr, hbuf, c0);
      moe_down_k<1><<<gB, blk, 0, stream>>>(hbuf, nullptr, Wd_s, nullptr, nullptr,
                                            cw, -1, out, c0);
    }
    for (int e = 0; e < NEXP; ++e) {
      const int* lst = lists + (size_t)e * T_TOK;
      const int* cptr = counts + (size_t)e * CNT_STRIDE;
      for (int c = 0; c < nchunks; ++c) {
        int c0 = c * cap;
        moe_gateup_k<1><<<gA, blk, 0, stream>>>(nullptr, x, nullptr, nullptr,
                                                Wg + (size_t)e * WSH, Wu + (size_t)e * WSH,
                                                lst, cptr, hbuf, c0);
        moe_down_k<1><<<gB, blk, 0, stream>>>(hbuf, nullptr, Wd + (size_t)e * WSH,
                                              lst, cptr, cw, e, out, c0);
      }
    }
  }
}

// Round 6
// 1216.154 us; speedup vs baseline: 1.1667x; 1.1667x over previous
//
#include <hip/hip_runtime.h>

#define T_TOK 16384
#define HDIM  1024
#define IDIM  2048
#define NEXP  8
#define CNT_STRIDE 32     // pad each expert counter to its own 128B cache line
#define TOK_PER_BLK 32    // tokens handled per 256-thread router block
#define MAX_TILES 400     // shared (128) + routed (<=264) 128-row tiles

typedef __attribute__((ext_vector_type(8))) short bf16x8;
typedef __attribute__((ext_vector_type(4))) float f32x4;
typedef unsigned short u16;
typedef unsigned int u32;

typedef __attribute__((address_space(1))) const unsigned int gas_u32;
typedef __attribute__((address_space(3))) unsigned int las_u32;

// async global->LDS, 16B per lane; LDS dest = base + lane*16 (wave-uniform base)
__device__ __forceinline__ void gl16(const void* g, void* l) {
  __builtin_amdgcn_global_load_lds((gas_u32*)g, (las_u32*)l, 16, 0, 0);
}

__device__ __forceinline__ u16 f2bf(float f) {
  union { float f; u32 i; } v; v.f = f;
  u32 r = v.i + 0x7FFF + ((v.i >> 16) & 1);  // RNE
  return (u16)(r >> 16);
}
__device__ __forceinline__ u32 pack2(float a, float b) {
  return (u32)f2bf(a) | ((u32)f2bf(b) << 16);
}

// ---------------- f32 -> bf16 elementwise convert ---------------------------
__global__ __launch_bounds__(256) void cvt_kernel(
    const float* __restrict__ s, u16* __restrict__ d, int n)
{
  int i = (blockIdx.x * 256 + threadIdx.x) * 4;
  if (i < n) {
    f32x4 v = *(const f32x4*)(s + i);
    uint2 o; o.x = pack2(v[0], v[1]); o.y = pack2(v[2], v[3]);
    *(uint2*)(d + i) = o;
  }
}

__global__ void init_counts(int* counts) {
  counts[threadIdx.x] = 0;  // launched with NEXP*CNT_STRIDE threads
}

// ---------------- zero-init out (all combines are atomic now) ---------------
__global__ __launch_bounds__(256) void zero_kernel(float* __restrict__ p, int n4) {
  f32x4 z = {0.f, 0.f, 0.f, 0.f};
  for (int i = blockIdx.x * 256 + threadIdx.x; i < n4; i += gridDim.x * 256)
    ((f32x4*)p)[i] = z;
}

// ---------------- router: f64 logits, top2 on logits ------------------------
__global__ __launch_bounds__(256) void router_kernel(
    const float* __restrict__ x, const float* __restrict__ Wr,
    const float* __restrict__ rb, float* __restrict__ cw,
    int* __restrict__ counts, int* __restrict__ lists)
{
  __shared__ __align__(16) float sWr[NEXP * HDIM];   // 32 KB
  __shared__ int pickE[2 * TOK_PER_BLK];
  __shared__ int pickT[2 * TOK_PER_BLK];

  const int tid = threadIdx.x;
  const int lane = tid & 63;
  const int wv = tid >> 6;

  for (int i = tid; i < NEXP * HDIM / 4; i += 256)
    ((f32x4*)sWr)[i] = ((const f32x4*)Wr)[i];

  float rbl[NEXP];
  #pragma unroll
  for (int e = 0; e < NEXP; ++e) rbl[e] = rb[e];

  __syncthreads();

  const int t_base = blockIdx.x * TOK_PER_BLK + wv * (TOK_PER_BLK / 4);
  for (int j = 0; j < TOK_PER_BLK / 4; ++j) {
    const int t = t_base + j;
    const float* xrow = x + (size_t)t * HDIM;
    f32x4 xv[4];
    #pragma unroll
    for (int c = 0; c < 4; ++c) xv[c] = *(const f32x4*)(xrow + c * 256 + lane * 4);

    double acc[NEXP];
    #pragma unroll
    for (int e = 0; e < NEXP; ++e) {
      const float* wr = sWr + e * HDIM;
      double a = 0.0;
      #pragma unroll
      for (int c = 0; c < 4; ++c) {
        f32x4 w4 = *(const f32x4*)(wr + c * 256 + lane * 4);
        a += (double)xv[c][0] * (double)w4[0];
        a += (double)xv[c][1] * (double)w4[1];
        a += (double)xv[c][2] * (double)w4[2];
        a += (double)xv[c][3] * (double)w4[3];
      }
      acc[e] = a;
    }
    #pragma unroll
    for (int e = 0; e < NEXP; ++e) {
      double a = acc[e];
      a += __shfl_xor(a, 1, 64);
      a += __shfl_xor(a, 2, 64);
      a += __shfl_xor(a, 4, 64);
      acc[e] = a;
    }
    double s0 = (lane & 1) ? acc[1] : acc[0];
    double s1 = (lane & 1) ? acc[3] : acc[2];
    double s2 = (lane & 1) ? acc[5] : acc[4];
    double s3 = (lane & 1) ? acc[7] : acc[6];
    double u0 = (lane & 2) ? s1 : s0;
    double u1 = (lane & 2) ? s3 : s2;
    double v  = (lane & 4) ? u1 : u0;
    v += __shfl_xor(v, 8, 64);
    v += __shfl_xor(v, 16, 64);
    v += __shfl_xor(v, 32, 64);
    double l[NEXP];
    #pragma unroll
    for (int e = 0; e < NEXP; ++e) l[e] = __shfl(v, e, 64) + (double)rbl[e];

    if (lane == 0) {
      int i1 = 0;
      #pragma unroll
      for (int e = 1; e < NEXP; ++e) if (l[e] > l[i1]) i1 = e;
      int i2 = -1;
      #pragma unroll
      for (int e = 0; e < NEXP; ++e) {
        if (e == i1) continue;
        if (i2 < 0 || l[e] > l[i2]) i2 = e;
      }
      float p1 = (float)(1.0 / (1.0 + exp(-l[i1])));
      float p2 = (float)(1.0 / (1.0 + exp(-l[i2])));
      cw[(size_t)t * NEXP + i1] = p1;
      cw[(size_t)t * NEXP + i2] = p2;
      int slot = (wv * (TOK_PER_BLK / 4) + j) * 2;
      pickE[slot] = i1; pickE[slot + 1] = i2;
      pickT[slot] = t;  pickT[slot + 1] = t;
    }
  }
  __syncthreads();

  const int myE = pickE[lane];
  const int myT = pickT[lane];
  #pragma unroll
  for (int ei = 0; ei < 2; ++ei) {
    int e = wv + ei * 4;
    unsigned long long b = __ballot(myE == e);
    int cnt = __popcll(b);
    int base = 0;
    if (lane == 0) base = atomicAdd(&counts[e * CNT_STRIDE], cnt);
    base = __shfl(base, 0, 64);
    if (myE == e)
      lists[(size_t)e * T_TOK + base + __popcll(b & ((1ull << lane) - 1))] = myT;
  }
}

// ------- merged 128-row tile descriptors: shared (e=-1) then routed ---------
__global__ void build_tiles(const int* __restrict__ counts,
                            int* __restrict__ td_e, int* __restrict__ td_r0,
                            int* __restrict__ ntiles)
{
  if (threadIdx.x == 0) {
    int n = 0;
    for (int r = 0; r < T_TOK; r += 128) { td_e[n] = -1; td_r0[n] = r; ++n; }
    for (int e = 0; e < NEXP; ++e) {
      int c = counts[e * CNT_STRIDE];
      for (int r = 0; r < c; r += 128) { td_e[n] = e; td_r0[n] = r; ++n; }
    }
    *ntiles = n;
  }
}

// ================= merged 2-phase GEMM cores, BK=64, swizzled ================
// Staging (per wave, per tile-column block of 64): chunk c covers 8 rows;
// lane l -> row +(l>>3), source 16B slot (l&7)^(l>>3); gl16 writes linearly.
// Read: logical slot (ks*4+quad) at row r lives at phys (ks*4+quad)^(r&7).
// (both-sides involution, validated in round 4: conflicts -> 0, results pass)

// ---------------- pass A: h = silu(X Wg^T) * (X Wu^T), all experts ----------
__global__ __launch_bounds__(256, 2) void gateup128f(
    const u16* __restrict__ xb,
    const u16* __restrict__ Wg_sh, const u16* __restrict__ Wu_sh,
    const u16* __restrict__ Wg_rt, const u16* __restrict__ Wu_rt,
    const int* __restrict__ lists, const int* __restrict__ counts,
    const int* __restrict__ td_e, const int* __restrict__ td_r0,
    const int* __restrict__ ntiles,
    u16* __restrict__ hbuf, int t0)
{
  __shared__ __align__(16) u16 sA[128 * 64];   // 16 KB
  __shared__ __align__(16) u16 sG[128 * 64];
  __shared__ __align__(16) u16 sU[128 * 64];

  const int ty = t0 + blockIdx.y;
  if (ty >= *ntiles) return;
  const int e = td_e[ty];
  const int r0 = td_r0[ty];
  const size_t WSH = (size_t)IDIM * HDIM;
  int cnt; const int* list; const u16 *Wg_e, *Wu_e;
  if (e < 0) { cnt = T_TOK; list = nullptr; Wg_e = Wg_sh; Wu_e = Wu_sh; }
  else {
    cnt = counts[e * CNT_STRIDE]; list = lists + (size_t)e * T_TOK;
    Wg_e = Wg_rt + (size_t)e * WSH; Wu_e = Wu_rt + (size_t)e * WSH;
  }
  const int n0 = blockIdx.x * 128;

  const int tid = threadIdx.x, lane = tid & 63, w = tid >> 6;
  const int wm = w & 1, wn = w >> 1;
  const int quad = lane >> 4, l15 = lane & 15, l7 = lane & 7;
  const int drow = lane >> 3;
  const int sslot = (lane & 7) ^ drow;

  const u16 *pa[4], *pg[4], *pu[4];
  u16 *dA[4], *dG[4], *dU[4];
  #pragma unroll
  for (int c = 0; c < 4; ++c) {
    int row = w * 32 + c * 8 + drow;
    int gi = r0 + row;
    int tok = list ? ((gi < cnt) ? list[gi] : 0) : gi;
    pa[c] = xb + (size_t)tok * HDIM + sslot * 8;
    pg[c] = Wg_e + (size_t)(n0 + row) * HDIM + sslot * 8;
    pu[c] = Wu_e + (size_t)(n0 + row) * HDIM + sslot * 8;
    dA[c] = sA + (w * 32 + c * 8) * 64;
    dG[c] = sG + (w * 32 + c * 8) * 64;
    dU[c] = sU + (w * 32 + c * 8) * 64;
  }

  const u16* fA = sA + (wm * 64 + l15) * 64;
  const u16* fG = sG + (wn * 64 + l15) * 64;
  const u16* fU = sU + (wn * 64 + l15) * 64;

  f32x4 accG[4][4] = {};
  f32x4 accU[4][4] = {};

  for (int kt = 0; kt < HDIM / 64; ++kt) {
    #pragma unroll
    for (int c = 0; c < 4; ++c) {
      gl16(pa[c] + kt * 64, dA[c]);
      gl16(pg[c] + kt * 64, dG[c]);
      gl16(pu[c] + kt * 64, dU[c]);
    }
    __syncthreads();
    #pragma unroll
    for (int ks = 0; ks < 2; ++ks) {
      const int sw = ((ks * 4 + quad) ^ l7) * 8;
      bf16x8 a[4], bg[4], bu[4];
      #pragma unroll
      for (int mt = 0; mt < 4; ++mt) a[mt] = *(const bf16x8*)(fA + mt * 1024 + sw);
      #pragma unroll
      for (int nt = 0; nt < 4; ++nt) {
        bg[nt] = *(const bf16x8*)(fG + nt * 1024 + sw);
        bu[nt] = *(const bf16x8*)(fU + nt * 1024 + sw);
      }
      #pragma unroll
      for (int nt = 0; nt < 4; ++nt) {
        #pragma unroll
        for (int mt = 0; mt < 4; ++mt) {
          accG[mt][nt] = __builtin_amdgcn_mfma_f32_16x16x32_bf16(a[mt], bg[nt], accG[mt][nt], 0, 0, 0);
          accU[mt][nt] = __builtin_amdgcn_mfma_f32_16x16x32_bf16(a[mt], bu[nt], accU[mt][nt], 0, 0, 0);
        }
      }
    }
    __syncthreads();
  }

  // hbuf rows are chunk-local: blockIdx.y*128 + local row (pad rows hold junk)
  #pragma unroll
  for (int mt = 0; mt < 4; ++mt) {
    #pragma unroll
    for (int i = 0; i < 4; ++i) {
      int rl = wm * 64 + mt * 16 + quad * 4 + i;
      u16* orow = hbuf + (size_t)(blockIdx.y * 128 + rl) * IDIM + n0 + wn * 64 + l15;
      #pragma unroll
      for (int nt = 0; nt < 4; ++nt) {
        float g = accG[mt][nt][i], u = accU[mt][nt][i];
        float h = (g / (1.f + __expf(-g))) * u;
        orow[nt * 16] = f2bf(h);
      }
    }
  }
}

// ---------------- pass B: out[tok] += s * (h Wd^T), 128x256 tiles -----------
__global__ __launch_bounds__(256, 2) void down256f(
    const u16* __restrict__ hbuf,
    const u16* __restrict__ Wd_sh, const u16* __restrict__ Wd_rt,
    const int* __restrict__ lists, const int* __restrict__ counts,
    const int* __restrict__ td_e, const int* __restrict__ td_r0,
    const int* __restrict__ ntiles,
    const float* __restrict__ cw, float* __restrict__ out, int t0)
{
  __shared__ __align__(16) u16 sA[128 * 64];   // 16 KB
  __shared__ __align__(16) u16 sB[256 * 64];   // 32 KB

  const int ty = t0 + blockIdx.y;
  if (ty >= *ntiles) return;
  const int e = td_e[ty];
  const int r0 = td_r0[ty];
  const size_t WSH = (size_t)IDIM * HDIM;
  int cnt; const int* list; const u16* Wd_e;
  if (e < 0) { cnt = T_TOK; list = nullptr; Wd_e = Wd_sh; }
  else {
    cnt = counts[e * CNT_STRIDE]; list = lists + (size_t)e * T_TOK;
    Wd_e = Wd_rt + (size_t)e * WSH;
  }
  const int n0 = blockIdx.x * 256;

  const int tid = threadIdx.x, lane = tid & 63, w = tid >> 6;
  const int wm = w & 1, wn = w >> 1;
  const int quad = lane >> 4, l15 = lane & 15, l7 = lane & 7;
  const int drow = lane >> 3;
  const int sslot = (lane & 7) ^ drow;

  const u16 *pa[4], *pb[8];
  u16 *dA[4], *dB[8];
  #pragma unroll
  for (int c = 0; c < 4; ++c) {
    int row = w * 32 + c * 8 + drow;
    pa[c] = hbuf + (size_t)(blockIdx.y * 128 + row) * IDIM + sslot * 8;
    dA[c] = sA + (w * 32 + c * 8) * 64;
  }
  #pragma unroll
  for (int c = 0; c < 8; ++c) {
    int row = w * 64 + c * 8 + drow;
    pb[c] = Wd_e + (size_t)(n0 + row) * IDIM + sslot * 8;
    dB[c] = sB + (w * 64 + c * 8) * 64;
  }

  const u16* fA = sA + (wm * 64 + l15) * 64;
  const u16* fB = sB + (wn * 128 + l15) * 64;

  f32x4 acc[4][8] = {};

  for (int kt = 0; kt < IDIM / 64; ++kt) {
    #pragma unroll
    for (int c = 0; c < 4; ++c) gl16(pa[c] + kt * 64, dA[c]);
    #pragma unroll
    for (int c = 0; c < 8; ++c) gl16(pb[c] + kt * 64, dB[c]);
    __syncthreads();
    #pragma unroll
    for (int ks = 0; ks < 2; ++ks) {
      const int sw = ((ks * 4 + quad) ^ l7) * 8;
      bf16x8 a[4], b[8];
      #pragma unroll
      for (int mt = 0; mt < 4; ++mt) a[mt] = *(const bf16x8*)(fA + mt * 1024 + sw);
      #pragma unroll
      for (int nt = 0; nt < 8; ++nt) b[nt] = *(const bf16x8*)(fB + nt * 1024 + sw);
      #pragma unroll
      for (int nt = 0; nt < 8; ++nt) {
        #pragma unroll
        for (int mt = 0; mt < 4; ++mt)
          acc[mt][nt] = __builtin_amdgcn_mfma_f32_16x16x32_bf16(a[mt], b[nt], acc[mt][nt], 0, 0, 0);
      }
    }
    __syncthreads();
  }

  #pragma unroll
  for (int mt = 0; mt < 4; ++mt) {
    #pragma unroll
    for (int i = 0; i < 4; ++i) {
      int rl = wm * 64 + mt * 16 + quad * 4 + i;
      if (r0 + rl < cnt) {
        int token = list ? list[r0 + rl] : (r0 + rl);
        float s = (e >= 0) ? cw[(size_t)token * NEXP + e] : 1.f;
        float* orow = out + (size_t)token * HDIM + n0 + wn * 128 + l15;
        #pragma unroll
        for (int nt = 0; nt < 8; ++nt)
          atomicAdd(&orow[nt * 16], s * acc[mt][nt][i]);
      }
    }
  }
}

// ============== fallback (small-ws) f32-source 128^2 kernels ================
__global__ __launch_bounds__(256, 2) void moe_gateup_k(
    const float* __restrict__ xf,
    const float* __restrict__ Wg_f, const float* __restrict__ Wu_f,
    const int* __restrict__ list, const int* __restrict__ count_ptr,
    u16* __restrict__ hbuf, int c0)
{
  __shared__ __align__(16) u16 sA[128 * 32];
  __shared__ __align__(16) u16 sG[128 * 32];
  __shared__ __align__(16) u16 sU[128 * 32];

  const int cnt = count_ptr ? *count_ptr : T_TOK;
  const int remain = cnt - c0;
  const int m0 = blockIdx.y * 128;
  if (m0 >= remain) return;
  const int n0 = blockIdx.x * 128;

  const int tid = threadIdx.x, lane = tid & 63, w = tid >> 6;
  const int wm = w & 1, wn = w >> 1;
  const int quad = lane >> 4, l15 = lane & 15;
  const int ar = lane >> 3, ac = lane & 7;

  const float *fa[4], *fg[4], *fu[4];
  int frow[4];
  #pragma unroll
  for (int p = 0; p < 4; ++p) {
    int row = w * 32 + p * 8 + ar;
    frow[p] = row;
    int gi = c0 + m0 + row;
    int tok = (gi < cnt) ? (list ? list[gi] : gi) : 0;
    fa[p] = xf + (size_t)tok * HDIM + ac * 4;
    fg[p] = Wg_f + (size_t)(n0 + row) * HDIM + ac * 4;
    fu[p] = Wu_f + (size_t)(n0 + row) * HDIM + ac * 4;
  }

  const u16* fA = sA + (wm * 64 + l15) * 32 + quad * 8;
  const u16* fG = sG + (wn * 64 + l15) * 32 + quad * 8;
  const u16* fU = sU + (wn * 64 + l15) * 32 + quad * 8;

  f32x4 accG[4][4] = {};
  f32x4 accU[4][4] = {};

  for (int kt = 0; kt < HDIM / 32; ++kt) {
    #pragma unroll
    for (int p = 0; p < 4; ++p) {
      f32x4 va = *(const f32x4*)(fa[p] + kt * 32);
      f32x4 vg = *(const f32x4*)(fg[p] + kt * 32);
      f32x4 vu = *(const f32x4*)(fu[p] + kt * 32);
      uint2 oa; oa.x = pack2(va[0], va[1]); oa.y = pack2(va[2], va[3]);
      uint2 og; og.x = pack2(vg[0], vg[1]); og.y = pack2(vg[2], vg[3]);
      uint2 ou; ou.x = pack2(vu[0], vu[1]); ou.y = pack2(vu[2], vu[3]);
      *(uint2*)(sA + frow[p] * 32 + ac * 4) = oa;
      *(uint2*)(sG + frow[p] * 32 + ac * 4) = og;
      *(uint2*)(sU + frow[p] * 32 + ac * 4) = ou;
    }
    __syncthreads();
    bf16x8 a[4];
    #pragma unroll
    for (int mt = 0; mt < 4; ++mt) a[mt] = *(const bf16x8*)(fA + mt * 16 * 32);
    #pragma unroll
    for (int nt = 0; nt < 4; ++nt) {
      bf16x8 bg = *(const bf16x8*)(fG + nt * 16 * 32);
      bf16x8 bu = *(const bf16x8*)(fU + nt * 16 * 32);
      #pragma unroll
      for (int mt = 0; mt < 4; ++mt) {
        accG[mt][nt] = __builtin_amdgcn_mfma_f32_16x16x32_bf16(a[mt], bg, accG[mt][nt], 0, 0, 0);
        accU[mt][nt] = __builtin_amdgcn_mfma_f32_16x16x32_bf16(a[mt], bu, accU[mt][nt], 0, 0, 0);
      }
    }
    __syncthreads();
  }

  #pragma unroll
  for (int mt = 0; mt < 4; ++mt) {
    #pragma unroll
    for (int i = 0; i < 4; ++i) {
      int row = m0 + wm * 64 + mt * 16 + quad * 4 + i;
      if (row < remain) {
        u16* orow = hbuf + (size_t)row * IDIM + n0 + wn * 64 + l15;
        #pragma unroll
        for (int nt = 0; nt < 4; ++nt) {
          float g = accG[mt][nt][i], u = accU[mt][nt][i];
          float h = (g / (1.f + __expf(-g))) * u;
          orow[nt * 16] = f2bf(h);
        }
      }
    }
  }
}

__global__ __launch_bounds__(256, 2) void moe_down_k(
    const u16* __restrict__ hbuf, const float* __restrict__ Wd_f,
    const int* __restrict__ list, const int* __restrict__ count_ptr,
    const float* __restrict__ cw, int expert, float* __restrict__ out, int c0)
{
  __shared__ __align__(16) u16 sA[128 * 32];
  __shared__ __align__(16) u16 sB[128 * 32];

  const int cnt = count_ptr ? *count_ptr : T_TOK;
  const int remain = cnt - c0;
  const int m0 = blockIdx.y * 128;
  if (m0 >= remain) return;
  const int n0 = blockIdx.x * 128;

  const int tid = threadIdx.x, lane = tid & 63, w = tid >> 6;
  const int wm = w & 1, wn = w >> 1;
  const int quad = lane >> 4, l15 = lane & 15;

  const int srow0 = w * 32 + (lane >> 2);
  const int srow1 = srow0 + 16;
  const int kch = (lane & 3) * 8;
  const int ar = lane >> 3, ac = lane & 7;

  const u16* pa0 = hbuf + (size_t)(m0 + srow0) * IDIM + kch;
  const u16* pa1 = hbuf + (size_t)(m0 + srow1) * IDIM + kch;
  const float* fb[4];
  int frow[4];
  #pragma unroll
  for (int p = 0; p < 4; ++p) {
    int row = w * 32 + p * 8 + ar;
    frow[p] = row;
    fb[p] = Wd_f + (size_t)(n0 + row) * IDIM + ac * 4;
  }

  const u16* fA = sA + (wm * 64 + l15) * 32 + quad * 8;
  const u16* fB = sB + (wn * 64 + l15) * 32 + quad * 8;

  f32x4 acc[4][4] = {};

  for (int kt = 0; kt < IDIM / 32; ++kt) {
    gl16(pa0 + kt * 32, sA + w * 1024);
    gl16(pa1 + kt * 32, sA + w * 1024 + 512);
    #pragma unroll
    for (int p = 0; p < 4; ++p) {
      f32x4 v = *(const f32x4*)(fb[p] + kt * 32);
      uint2 o; o.x = pack2(v[0], v[1]); o.y = pack2(v[2], v[3]);
      *(uint2*)(sB + frow[p] * 32 + ac * 4) = o;
    }
    __syncthreads();
    bf16x8 a[4];
    #pragma unroll
    for (int mt = 0; mt < 4; ++mt) a[mt] = *(const bf16x8*)(fA + mt * 16 * 32);
    #pragma unroll
    for (int nt = 0; nt < 4; ++nt) {
      bf16x8 b = *(const bf16x8*)(fB + nt * 16 * 32);
      #pragma unroll
      for (int mt = 0; mt < 4; ++mt)
        acc[mt][nt] = __builtin_amdgcn_mfma_f32_16x16x32_bf16(a[mt], b, acc[mt][nt], 0, 0, 0);
    }
    __syncthreads();
  }

  #pragma unroll
  for (int mt = 0; mt < 4; ++mt) {
    #pragma unroll
    for (int i = 0; i < 4; ++i) {
      int rl = m0 + wm * 64 + mt * 16 + quad * 4 + i;
      if (rl < remain) {
        int token = list ? list[c0 + rl] : (c0 + rl);
        float s = (expert >= 0) ? cw[(size_t)token * NEXP + expert] : 1.f;
        float* orow = out + (size_t)token * HDIM + n0 + wn * 64 + l15;
        #pragma unroll
        for (int nt = 0; nt < 4; ++nt) {
          float v = s * acc[mt][nt][i];
          if (expert >= 0) v += orow[nt * 16];
          orow[nt * 16] = v;
        }
      }
    }
  }
}

extern "C" void kernel_launch(void* const* d_in, const int* in_sizes, int n_in,
                              void* d_out, int out_size, void* d_ws, size_t ws_size,
                              hipStream_t stream) {
  (void)in_sizes; (void)n_in; (void)out_size;
  const float* x    = (const float*)d_in[0];
  const float* Wg_s = (const float*)d_in[1];
  const float* Wu_s = (const float*)d_in[2];
  const float* Wd_s = (const float*)d_in[3];
  const float* Wg   = (const float*)d_in[4];
  const float* Wu   = (const float*)d_in[5];
  const float* Wd   = (const float*)d_in[6];
  const float* Wr   = (const float*)d_in[7];
  const float* rb   = (const float*)d_in[8];
  float* out = (float*)d_out;

  char* ws = (char*)d_ws;
  size_t off = 1024;               // counts: NEXP * CNT_STRIDE ints = 1 KB
  int* counts = (int*)ws;
  int* lists = (int*)(ws + off);  off += (size_t)NEXP * T_TOK * 4;
  float* cw = (float*)(ws + off); off += (size_t)T_TOK * NEXP * 4;
  int* td = (int*)(ws + off);     off += 3328;  // td_e | td_r0 | ntiles
  int* td_e = td;
  int* td_r0 = td + MAX_TILES;
  int* ntiles = td + 2 * MAX_TILES;

  const size_t WSH = (size_t)IDIM * HDIM;
  const size_t xc_elems = (size_t)T_TOK * HDIM;
  const size_t wc_elems = 3 * WSH + 3 * NEXP * WSH;   // 27*WSH
  const size_t fast_need = off + (xc_elems + wc_elems) * 2 + (size_t)2048 * IDIM * 2;
  const bool fast = ws_size >= fast_need;

  u16* xc = (u16*)(ws + off);
  u16* wgs_c = xc + (fast ? xc_elems : 0);
  u16* wus_c = wgs_c + WSH;
  u16* wds_c = wus_c + WSH;
  u16* wg_c = wds_c + WSH;
  u16* wu_c = wg_c + NEXP * WSH;
  u16* wd_c = wu_c + NEXP * WSH;

  size_t hoff = off + (fast ? (xc_elems + wc_elems) * 2 : 0);
  u16* hbuf = (u16*)(ws + hoff);

  size_t avail = (ws_size > hoff) ? (ws_size - hoff) : 0;
  long long capll = (long long)(avail / ((size_t)IDIM * 2));
  int cap = (capll > (long long)MAX_TILES * 128) ? MAX_TILES * 128 : (int)capll;
  cap &= ~127;
  if (cap < 128) cap = 128;

  init_counts<<<1, NEXP * CNT_STRIDE, 0, stream>>>(counts);
  if (fast) {
    zero_kernel<<<2048, 256, 0, stream>>>(out, (int)(xc_elems / 4));
    auto cv = [&](const float* s, u16* d, size_t n) {
      int blocks = (int)((n / 4 + 255) / 256);
      cvt_kernel<<<blocks, 256, 0, stream>>>(s, d, (int)n);
    };
    cv(x, xc, xc_elems);
    cv(Wg_s, wgs_c, WSH); cv(Wu_s, wus_c, WSH); cv(Wd_s, wds_c, WSH);
    cv(Wg, wg_c, NEXP * WSH); cv(Wu, wu_c, NEXP * WSH); cv(Wd, wd_c, NEXP * WSH);
  }
  router_kernel<<<T_TOK / TOK_PER_BLK, 256, 0, stream>>>(x, Wr, rb, cw, counts, lists);

  if (fast) {
    // merged shared+routed tile list; both passes single-kernel per chunk;
    // all output combines atomic into zeroed out
    build_tiles<<<1, 64, 0, stream>>>(counts, td_e, td_r0, ntiles);
    int tpc = cap / 128;
    for (int t0 = 0; t0 < MAX_TILES; t0 += tpc) {
      int yt = (MAX_TILES - t0 < tpc) ? (MAX_TILES - t0) : tpc;
      gateup128f<<<dim3(IDIM / 128, yt), 256, 0, stream>>>(
          xc, wgs_c, wus_c, wg_c, wu_c, lists, counts, td_e, td_r0, ntiles, hbuf, t0);
      down256f<<<dim3(HDIM / 256, yt), 256, 0, stream>>>(
          hbuf, wds_c, wd_c, lists, counts, td_e, td_r0, ntiles, cw, out, t0);
    }
  } else {
    // fallback: f32-source 128^2 path, serialized per-expert RMW
    int fcap = cap;
    int nchunks = (T_TOK + fcap - 1) / fcap;
    dim3 blk(256);
    dim3 gA(IDIM / 128, fcap / 128);
    dim3 gB(HDIM / 128, fcap / 128);
    for (int c = 0; c < nchunks; ++c) {
      int c0 = c * fcap;
      moe_gateup_k<<<gA, blk, 0, stream>>>(x, Wg_s, Wu_s, nullptr, nullptr, hbuf, c0);
      moe_down_k<<<gB, blk, 0, stream>>>(hbuf, Wd_s, nullptr, nullptr, cw, -1, out, c0);
    }
    for (int e = 0; e < NEXP; ++e) {
      const int* lst = lists + (size_t)e * T_TOK;
      const int* cptr = counts + (size_t)e * CNT_STRIDE;
      for (int c = 0; c < nchunks; ++c) {
        int c0 = c * fcap;
        moe_gateup_k<<<gA, blk, 0, stream>>>(x, Wg + (size_t)e * WSH, Wu + (size_t)e * WSH,
                                             lst, cptr, hbuf, c0);
        moe_down_k<<<gB, blk, 0, stream>>>(hbuf, Wd + (size_t)e * WSH,
                                           lst, cptr, cw, e, out, c0);
      }
    }
  }
}

// Round 7
// 1156.181 us; speedup vs baseline: 1.2273x; 1.0519x over previous
//
#include <hip/hip_runtime.h>

#define T_TOK 16384
#define HDIM  1024
#define IDIM  2048
#define NEXP  8
#define CNT_STRIDE 32     // pad each expert counter to its own 128B cache line
#define TOK_PER_BLK 32    // tokens handled per 256-thread router block
#define MAX_RT 264        // max routed 128-row tiles (2*T_TOK/128 + 8 pads)
#define SH_TILES (T_TOK / 128)

typedef __attribute__((ext_vector_type(8))) short bf16x8;
typedef __attribute__((ext_vector_type(4))) float f32x4;
typedef unsigned short u16;
typedef unsigned int u32;

typedef __attribute__((address_space(1))) const unsigned int gas_u32;
typedef __attribute__((address_space(3))) unsigned int las_u32;

// async global->LDS, 16B per lane; LDS dest = base + lane*16 (wave-uniform base)
__device__ __forceinline__ void gl16(const void* g, void* l) {
  __builtin_amdgcn_global_load_lds((gas_u32*)g, (las_u32*)l, 16, 0, 0);
}

__device__ __forceinline__ u16 f2bf(float f) {
  union { float f; u32 i; } v; v.f = f;
  u32 r = v.i + 0x7FFF + ((v.i >> 16) & 1);  // RNE
  return (u16)(r >> 16);
}
__device__ __forceinline__ u32 pack2(float a, float b) {
  return (u32)f2bf(a) | ((u32)f2bf(b) << 16);
}

// ---------------- f32 -> bf16 elementwise converts --------------------------
__global__ __launch_bounds__(256) void cvt_kernel(
    const float* __restrict__ s, u16* __restrict__ d, int n)
{
  int i = (blockIdx.x * 256 + threadIdx.x) * 4;
  if (i < n) {
    f32x4 v = *(const f32x4*)(s + i);
    uint2 o; o.x = pack2(v[0], v[1]); o.y = pack2(v[2], v[3]);
    *(uint2*)(d + i) = o;
  }
}

// batched: blockIdx.z selects among 3 equally-sized arrays
__global__ __launch_bounds__(256) void cvt3_kernel(
    const float* __restrict__ s0, const float* __restrict__ s1,
    const float* __restrict__ s2,
    u16* __restrict__ d0, u16* __restrict__ d1, u16* __restrict__ d2, int n)
{
  const float* s = (blockIdx.z == 0) ? s0 : (blockIdx.z == 1) ? s1 : s2;
  u16* d = (blockIdx.z == 0) ? d0 : (blockIdx.z == 1) ? d1 : d2;
  int i = (blockIdx.x * 256 + threadIdx.x) * 4;
  if (i < n) {
    f32x4 v = *(const f32x4*)(s + i);
    uint2 o; o.x = pack2(v[0], v[1]); o.y = pack2(v[2], v[3]);
    *(uint2*)(d + i) = o;
  }
}

__global__ void init_counts(int* counts) {
  counts[threadIdx.x] = 0;  // launched with NEXP*CNT_STRIDE threads
}

// ---------------- router: f64 logits, top2 on logits ------------------------
__global__ __launch_bounds__(256) void router_kernel(
    const float* __restrict__ x, const float* __restrict__ Wr,
    const float* __restrict__ rb, float* __restrict__ cw,
    int* __restrict__ counts, int* __restrict__ lists)
{
  __shared__ __align__(16) float sWr[NEXP * HDIM];   // 32 KB
  __shared__ int pickE[2 * TOK_PER_BLK];
  __shared__ int pickT[2 * TOK_PER_BLK];

  const int tid = threadIdx.x;
  const int lane = tid & 63;
  const int wv = tid >> 6;

  for (int i = tid; i < NEXP * HDIM / 4; i += 256)
    ((f32x4*)sWr)[i] = ((const f32x4*)Wr)[i];

  float rbl[NEXP];
  #pragma unroll
  for (int e = 0; e < NEXP; ++e) rbl[e] = rb[e];

  __syncthreads();

  const int t_base = blockIdx.x * TOK_PER_BLK + wv * (TOK_PER_BLK / 4);
  for (int j = 0; j < TOK_PER_BLK / 4; ++j) {
    const int t = t_base + j;
    const float* xrow = x + (size_t)t * HDIM;
    f32x4 xv[4];
    #pragma unroll
    for (int c = 0; c < 4; ++c) xv[c] = *(const f32x4*)(xrow + c * 256 + lane * 4);

    double acc[NEXP];
    #pragma unroll
    for (int e = 0; e < NEXP; ++e) {
      const float* wr = sWr + e * HDIM;
      double a = 0.0;
      #pragma unroll
      for (int c = 0; c < 4; ++c) {
        f32x4 w4 = *(const f32x4*)(wr + c * 256 + lane * 4);
        a += (double)xv[c][0] * (double)w4[0];
        a += (double)xv[c][1] * (double)w4[1];
        a += (double)xv[c][2] * (double)w4[2];
        a += (double)xv[c][3] * (double)w4[3];
      }
      acc[e] = a;
    }
    #pragma unroll
    for (int e = 0; e < NEXP; ++e) {
      double a = acc[e];
      a += __shfl_xor(a, 1, 64);
      a += __shfl_xor(a, 2, 64);
      a += __shfl_xor(a, 4, 64);
      acc[e] = a;
    }
    double s0 = (lane & 1) ? acc[1] : acc[0];
    double s1 = (lane & 1) ? acc[3] : acc[2];
    double s2 = (lane & 1) ? acc[5] : acc[4];
    double s3 = (lane & 1) ? acc[7] : acc[6];
    double u0 = (lane & 2) ? s1 : s0;
    double u1 = (lane & 2) ? s3 : s2;
    double v  = (lane & 4) ? u1 : u0;
    v += __shfl_xor(v, 8, 64);
    v += __shfl_xor(v, 16, 64);
    v += __shfl_xor(v, 32, 64);
    double l[NEXP];
    #pragma unroll
    for (int e = 0; e < NEXP; ++e) l[e] = __shfl(v, e, 64) + (double)rbl[e];

    if (lane == 0) {
      int i1 = 0;
      #pragma unroll
      for (int e = 1; e < NEXP; ++e) if (l[e] > l[i1]) i1 = e;
      int i2 = -1;
      #pragma unroll
      for (int e = 0; e < NEXP; ++e) {
        if (e == i1) continue;
        if (i2 < 0 || l[e] > l[i2]) i2 = e;
      }
      float p1 = (float)(1.0 / (1.0 + exp(-l[i1])));
      float p2 = (float)(1.0 / (1.0 + exp(-l[i2])));
      cw[(size_t)t * NEXP + i1] = p1;
      cw[(size_t)t * NEXP + i2] = p2;
      int slot = (wv * (TOK_PER_BLK / 4) + j) * 2;
      pickE[slot] = i1; pickE[slot + 1] = i2;
      pickT[slot] = t;  pickT[slot + 1] = t;
    }
  }
  __syncthreads();

  const int myE = pickE[lane];
  const int myT = pickT[lane];
  #pragma unroll
  for (int ei = 0; ei < 2; ++ei) {
    int e = wv + ei * 4;
    unsigned long long b = __ballot(myE == e);
    int cnt = __popcll(b);
    int base = 0;
    if (lane == 0) base = atomicAdd(&counts[e * CNT_STRIDE], cnt);
    base = __shfl(base, 0, 64);
    if (myE == e)
      lists[(size_t)e * T_TOK + base + __popcll(b & ((1ull << lane) - 1))] = myT;
  }
}

// ------------- routed 128-row tile descriptors (shared handled dense) -------
__global__ void build_tiles(const int* __restrict__ counts,
                            int* __restrict__ td_e, int* __restrict__ td_r0,
                            int* __restrict__ ntiles)
{
  if (threadIdx.x == 0) {
    int n = 0;
    for (int e = 0; e < NEXP; ++e) {
      int c = counts[e * CNT_STRIDE];
      for (int r = 0; r < c; r += 128) { td_e[n] = e; td_r0[n] = r; ++n; }
    }
    *ntiles = n;
  }
}

// ================= 2-phase GEMM cores, BK=64, swizzled (proven R6) ==========
// Staging: chunk c covers 8 rows; lane l -> row +(l>>3), src 16B slot
// (l&7)^(l>>3); gl16 writes linearly. Read: logical slot (ks*4+quad) at row r
// lives at phys (ks*4+quad)^(r&7). Both-sides involution; conflicts == 0.
// ROUTED=0: dense shared-expert tiles (r0 from blockIdx), store epilogue.
// ROUTED=1: expert tile list, gathered rows, atomic epilogue (down).

// ---------------- pass A: h = silu(X Wg^T) * (X Wu^T) -----------------------
__global__ __launch_bounds__(256, 2) void gateup128f(
    const u16* __restrict__ xb,
    const u16* __restrict__ Wg_sh, const u16* __restrict__ Wu_sh,
    const u16* __restrict__ Wg_rt, const u16* __restrict__ Wu_rt,
    const int* __restrict__ lists, const int* __restrict__ counts,
    const int* __restrict__ td_e, const int* __restrict__ td_r0,
    const int* __restrict__ ntiles,
    u16* __restrict__ hbuf, int t0, int routed)
{
  __shared__ __align__(16) u16 sA[128 * 64];   // 16 KB
  __shared__ __align__(16) u16 sG[128 * 64];
  __shared__ __align__(16) u16 sU[128 * 64];

  const size_t WSH = (size_t)IDIM * HDIM;
  int r0, cnt; const int* list; const u16 *Wg_e, *Wu_e;
  if (routed) {
    int ty = t0 + blockIdx.y;
    if (ty >= *ntiles) return;
    int e = td_e[ty]; r0 = td_r0[ty]; cnt = counts[e * CNT_STRIDE];
    list = lists + (size_t)e * T_TOK;
    Wg_e = Wg_rt + (size_t)e * WSH; Wu_e = Wu_rt + (size_t)e * WSH;
  } else {
    r0 = (t0 + blockIdx.y) * 128; cnt = T_TOK; list = nullptr;
    Wg_e = Wg_sh; Wu_e = Wu_sh;
  }
  const int n0 = blockIdx.x * 128;

  const int tid = threadIdx.x, lane = tid & 63, w = tid >> 6;
  const int wm = w & 1, wn = w >> 1;
  const int quad = lane >> 4, l15 = lane & 15, l7 = lane & 7;
  const int drow = lane >> 3;
  const int sslot = (lane & 7) ^ drow;

  const u16 *pa[4], *pg[4], *pu[4];
  u16 *dA[4], *dG[4], *dU[4];
  #pragma unroll
  for (int c = 0; c < 4; ++c) {
    int row = w * 32 + c * 8 + drow;
    int gi = r0 + row;
    int tok = list ? ((gi < cnt) ? list[gi] : 0) : gi;
    pa[c] = xb + (size_t)tok * HDIM + sslot * 8;
    pg[c] = Wg_e + (size_t)(n0 + row) * HDIM + sslot * 8;
    pu[c] = Wu_e + (size_t)(n0 + row) * HDIM + sslot * 8;
    dA[c] = sA + (w * 32 + c * 8) * 64;
    dG[c] = sG + (w * 32 + c * 8) * 64;
    dU[c] = sU + (w * 32 + c * 8) * 64;
  }

  const u16* fA = sA + (wm * 64 + l15) * 64;
  const u16* fG = sG + (wn * 64 + l15) * 64;
  const u16* fU = sU + (wn * 64 + l15) * 64;

  f32x4 accG[4][4] = {};
  f32x4 accU[4][4] = {};

  for (int kt = 0; kt < HDIM / 64; ++kt) {
    #pragma unroll
    for (int c = 0; c < 4; ++c) {
      gl16(pa[c] + kt * 64, dA[c]);
      gl16(pg[c] + kt * 64, dG[c]);
      gl16(pu[c] + kt * 64, dU[c]);
    }
    __syncthreads();
    #pragma unroll
    for (int ks = 0; ks < 2; ++ks) {
      const int sw = ((ks * 4 + quad) ^ l7) * 8;
      bf16x8 a[4], bg[4], bu[4];
      #pragma unroll
      for (int mt = 0; mt < 4; ++mt) a[mt] = *(const bf16x8*)(fA + mt * 1024 + sw);
      #pragma unroll
      for (int nt = 0; nt < 4; ++nt) {
        bg[nt] = *(const bf16x8*)(fG + nt * 1024 + sw);
        bu[nt] = *(const bf16x8*)(fU + nt * 1024 + sw);
      }
      #pragma unroll
      for (int nt = 0; nt < 4; ++nt) {
        #pragma unroll
        for (int mt = 0; mt < 4; ++mt) {
          accG[mt][nt] = __builtin_amdgcn_mfma_f32_16x16x32_bf16(a[mt], bg[nt], accG[mt][nt], 0, 0, 0);
          accU[mt][nt] = __builtin_amdgcn_mfma_f32_16x16x32_bf16(a[mt], bu[nt], accU[mt][nt], 0, 0, 0);
        }
      }
    }
    __syncthreads();
  }

  // hbuf rows are chunk-local: blockIdx.y*128 + local row
  #pragma unroll
  for (int mt = 0; mt < 4; ++mt) {
    #pragma unroll
    for (int i = 0; i < 4; ++i) {
      int rl = wm * 64 + mt * 16 + quad * 4 + i;
      u16* orow = hbuf + (size_t)(blockIdx.y * 128 + rl) * IDIM + n0 + wn * 64 + l15;
      #pragma unroll
      for (int nt = 0; nt < 4; ++nt) {
        float g = accG[mt][nt][i], u = accU[mt][nt][i];
        float h = (g / (1.f + __expf(-g))) * u;
        orow[nt * 16] = f2bf(h);
      }
    }
  }
}

// ---------------- pass B: out[tok] (store | += cw*) (h Wd^T), 128x256 -------
__global__ __launch_bounds__(256, 2) void down256f(
    const u16* __restrict__ hbuf,
    const u16* __restrict__ Wd_sh, const u16* __restrict__ Wd_rt,
    const int* __restrict__ lists, const int* __restrict__ counts,
    const int* __restrict__ td_e, const int* __restrict__ td_r0,
    const int* __restrict__ ntiles,
    const float* __restrict__ cw, float* __restrict__ out, int t0, int routed)
{
  __shared__ __align__(16) u16 sA[128 * 64];   // 16 KB
  __shared__ __align__(16) u16 sB[256 * 64];   // 32 KB

  const size_t WSH = (size_t)IDIM * HDIM;
  int e = -1, r0, cnt; const int* list; const u16* Wd_e;
  if (routed) {
    int ty = t0 + blockIdx.y;
    if (ty >= *ntiles) return;
    e = td_e[ty]; r0 = td_r0[ty]; cnt = counts[e * CNT_STRIDE];
    list = lists + (size_t)e * T_TOK;
    Wd_e = Wd_rt + (size_t)e * WSH;
  } else {
    r0 = (t0 + blockIdx.y) * 128; cnt = T_TOK; list = nullptr;
    Wd_e = Wd_sh;
  }
  const int n0 = blockIdx.x * 256;

  const int tid = threadIdx.x, lane = tid & 63, w = tid >> 6;
  const int wm = w & 1, wn = w >> 1;
  const int quad = lane >> 4, l15 = lane & 15, l7 = lane & 7;
  const int drow = lane >> 3;
  const int sslot = (lane & 7) ^ drow;

  const u16 *pa[4], *pb[8];
  u16 *dA[4], *dB[8];
  #pragma unroll
  for (int c = 0; c < 4; ++c) {
    int row = w * 32 + c * 8 + drow;
    pa[c] = hbuf + (size_t)(blockIdx.y * 128 + row) * IDIM + sslot * 8;
    dA[c] = sA + (w * 32 + c * 8) * 64;
  }
  #pragma unroll
  for (int c = 0; c < 8; ++c) {
    int row = w * 64 + c * 8 + drow;
    pb[c] = Wd_e + (size_t)(n0 + row) * IDIM + sslot * 8;
    dB[c] = sB + (w * 64 + c * 8) * 64;
  }

  const u16* fA = sA + (wm * 64 + l15) * 64;
  const u16* fB = sB + (wn * 128 + l15) * 64;

  f32x4 acc[4][8] = {};

  for (int kt = 0; kt < IDIM / 64; ++kt) {
    #pragma unroll
    for (int c = 0; c < 4; ++c) gl16(pa[c] + kt * 64, dA[c]);
    #pragma unroll
    for (int c = 0; c < 8; ++c) gl16(pb[c] + kt * 64, dB[c]);
    __syncthreads();
    #pragma unroll
    for (int ks = 0; ks < 2; ++ks) {
      const int sw = ((ks * 4 + quad) ^ l7) * 8;
      bf16x8 a[4], b[8];
      #pragma unroll
      for (int mt = 0; mt < 4; ++mt) a[mt] = *(const bf16x8*)(fA + mt * 1024 + sw);
      #pragma unroll
      for (int nt = 0; nt < 8; ++nt) b[nt] = *(const bf16x8*)(fB + nt * 1024 + sw);
      #pragma unroll
      for (int nt = 0; nt < 8; ++nt) {
        #pragma unroll
        for (int mt = 0; mt < 4; ++mt)
          acc[mt][nt] = __builtin_amdgcn_mfma_f32_16x16x32_bf16(a[mt], b[nt], acc[mt][nt], 0, 0, 0);
      }
    }
    __syncthreads();
  }

  #pragma unroll
  for (int mt = 0; mt < 4; ++mt) {
    #pragma unroll
    for (int i = 0; i < 4; ++i) {
      int rl = wm * 64 + mt * 16 + quad * 4 + i;
      if (r0 + rl < cnt) {
        if (routed) {
          int token = list[r0 + rl];
          float s = cw[(size_t)token * NEXP + e];
          float* orow = out + (size_t)token * HDIM + n0 + wn * 128 + l15;
          #pragma unroll
          for (int nt = 0; nt < 8; ++nt)
            atomicAdd(&orow[nt * 16], s * acc[mt][nt][i]);
        } else {
          float* orow = out + (size_t)(r0 + rl) * HDIM + n0 + wn * 128 + l15;
          #pragma unroll
          for (int nt = 0; nt < 8; ++nt)
            orow[nt * 16] = acc[mt][nt][i];
        }
      }
    }
  }
}

// ============== fallback (small-ws) f32-source 128^2 kernels ================
__global__ __launch_bounds__(256, 2) void moe_gateup_k(
    const float* __restrict__ xf,
    const float* __restrict__ Wg_f, const float* __restrict__ Wu_f,
    const int* __restrict__ list, const int* __restrict__ count_ptr,
    u16* __restrict__ hbuf, int c0)
{
  __shared__ __align__(16) u16 sA[128 * 32];
  __shared__ __align__(16) u16 sG[128 * 32];
  __shared__ __align__(16) u16 sU[128 * 32];

  const int cnt = count_ptr ? *count_ptr : T_TOK;
  const int remain = cnt - c0;
  const int m0 = blockIdx.y * 128;
  if (m0 >= remain) return;
  const int n0 = blockIdx.x * 128;

  const int tid = threadIdx.x, lane = tid & 63, w = tid >> 6;
  const int wm = w & 1, wn = w >> 1;
  const int quad = lane >> 4, l15 = lane & 15;
  const int ar = lane >> 3, ac = lane & 7;

  const float *fa[4], *fg[4], *fu[4];
  int frow[4];
  #pragma unroll
  for (int p = 0; p < 4; ++p) {
    int row = w * 32 + p * 8 + ar;
    frow[p] = row;
    int gi = c0 + m0 + row;
    int tok = (gi < cnt) ? (list ? list[gi] : gi) : 0;
    fa[p] = xf + (size_t)tok * HDIM + ac * 4;
    fg[p] = Wg_f + (size_t)(n0 + row) * HDIM + ac * 4;
    fu[p] = Wu_f + (size_t)(n0 + row) * HDIM + ac * 4;
  }

  const u16* fA = sA + (wm * 64 + l15) * 32 + quad * 8;
  const u16* fG = sG + (wn * 64 + l15) * 32 + quad * 8;
  const u16* fU = sU + (wn * 64 + l15) * 32 + quad * 8;

  f32x4 accG[4][4] = {};
  f32x4 accU[4][4] = {};

  for (int kt = 0; kt < HDIM / 32; ++kt) {
    #pragma unroll
    for (int p = 0; p < 4; ++p) {
      f32x4 va = *(const f32x4*)(fa[p] + kt * 32);
      f32x4 vg = *(const f32x4*)(fg[p] + kt * 32);
      f32x4 vu = *(const f32x4*)(fu[p] + kt * 32);
      uint2 oa; oa.x = pack2(va[0], va[1]); oa.y = pack2(va[2], va[3]);
      uint2 og; og.x = pack2(vg[0], vg[1]); og.y = pack2(vg[2], vg[3]);
      uint2 ou; ou.x = pack2(vu[0], vu[1]); ou.y = pack2(vu[2], vu[3]);
      *(uint2*)(sA + frow[p] * 32 + ac * 4) = oa;
      *(uint2*)(sG + frow[p] * 32 + ac * 4) = og;
      *(uint2*)(sU + frow[p] * 32 + ac * 4) = ou;
    }
    __syncthreads();
    bf16x8 a[4];
    #pragma unroll
    for (int mt = 0; mt < 4; ++mt) a[mt] = *(const bf16x8*)(fA + mt * 16 * 32);
    #pragma unroll
    for (int nt = 0; nt < 4; ++nt) {
      bf16x8 bg = *(const bf16x8*)(fG + nt * 16 * 32);
      bf16x8 bu = *(const bf16x8*)(fU + nt * 16 * 32);
      #pragma unroll
      for (int mt = 0; mt < 4; ++mt) {
        accG[mt][nt] = __builtin_amdgcn_mfma_f32_16x16x32_bf16(a[mt], bg, accG[mt][nt], 0, 0, 0);
        accU[mt][nt] = __builtin_amdgcn_mfma_f32_16x16x32_bf16(a[mt], bu, accU[mt][nt], 0, 0, 0);
      }
    }
    __syncthreads();
  }

  #pragma unroll
  for (int mt = 0; mt < 4; ++mt) {
    #pragma unroll
    for (int i = 0; i < 4; ++i) {
      int row = m0 + wm * 64 + mt * 16 + quad * 4 + i;
      if (row < remain) {
        u16* orow = hbuf + (size_t)row * IDIM + n0 + wn * 64 + l15;
        #pragma unroll
        for (int nt = 0; nt < 4; ++nt) {
          float g = accG[mt][nt][i], u = accU[mt][nt][i];
          float h = (g / (1.f + __expf(-g))) * u;
          orow[nt * 16] = f2bf(h);
        }
      }
    }
  }
}

__global__ __launch_bounds__(256, 2) void moe_down_k(
    const u16* __restrict__ hbuf, const float* __restrict__ Wd_f,
    const int* __restrict__ list, const int* __restrict__ count_ptr,
    const float* __restrict__ cw, int expert, float* __restrict__ out, int c0)
{
  __shared__ __align__(16) u16 sA[128 * 32];
  __shared__ __align__(16) u16 sB[128 * 32];

  const int cnt = count_ptr ? *count_ptr : T_TOK;
  const int remain = cnt - c0;
  const int m0 = blockIdx.y * 128;
  if (m0 >= remain) return;
  const int n0 = blockIdx.x * 128;

  const int tid = threadIdx.x, lane = tid & 63, w = tid >> 6;
  const int wm = w & 1, wn = w >> 1;
  const int quad = lane >> 4, l15 = lane & 15;

  const int srow0 = w * 32 + (lane >> 2);
  const int srow1 = srow0 + 16;
  const int kch = (lane & 3) * 8;
  const int ar = lane >> 3, ac = lane & 7;

  const u16* pa0 = hbuf + (size_t)(m0 + srow0) * IDIM + kch;
  const u16* pa1 = hbuf + (size_t)(m0 + srow1) * IDIM + kch;
  const float* fb[4];
  int frow[4];
  #pragma unroll
  for (int p = 0; p < 4; ++p) {
    int row = w * 32 + p * 8 + ar;
    frow[p] = row;
    fb[p] = Wd_f + (size_t)(n0 + row) * IDIM + ac * 4;
  }

  const u16* fA = sA + (wm * 64 + l15) * 32 + quad * 8;
  const u16* fB = sB + (wn * 64 + l15) * 32 + quad * 8;

  f32x4 acc[4][4] = {};

  for (int kt = 0; kt < IDIM / 32; ++kt) {
    gl16(pa0 + kt * 32, sA + w * 1024);
    gl16(pa1 + kt * 32, sA + w * 1024 + 512);
    #pragma unroll
    for (int p = 0; p < 4; ++p) {
      f32x4 v = *(const f32x4*)(fb[p] + kt * 32);
      uint2 o; o.x = pack2(v[0], v[1]); o.y = pack2(v[2], v[3]);
      *(uint2*)(sB + frow[p] * 32 + ac * 4) = o;
    }
    __syncthreads();
    bf16x8 a[4];
    #pragma unroll
    for (int mt = 0; mt < 4; ++mt) a[mt] = *(const bf16x8*)(fA + mt * 16 * 32);
    #pragma unroll
    for (int nt = 0; nt < 4; ++nt) {
      bf16x8 b = *(const bf16x8*)(fB + nt * 16 * 32);
      #pragma unroll
      for (int mt = 0; mt < 4; ++mt)
        acc[mt][nt] = __builtin_amdgcn_mfma_f32_16x16x32_bf16(a[mt], b, acc[mt][nt], 0, 0, 0);
    }
    __syncthreads();
  }

  #pragma unroll
  for (int mt = 0; mt < 4; ++mt) {
    #pragma unroll
    for (int i = 0; i < 4; ++i) {
      int rl = m0 + wm * 64 + mt * 16 + quad * 4 + i;
      if (rl < remain) {
        int token = list ? list[c0 + rl] : (c0 + rl);
        float s = (expert >= 0) ? cw[(size_t)token * NEXP + expert] : 1.f;
        float* orow = out + (size_t)token * HDIM + n0 + wn * 64 + l15;
        #pragma unroll
        for (int nt = 0; nt < 4; ++nt) {
          float v = s * acc[mt][nt][i];
          if (expert >= 0) v += orow[nt * 16];
          orow[nt * 16] = v;
        }
      }
    }
  }
}

extern "C" void kernel_launch(void* const* d_in, const int* in_sizes, int n_in,
                              void* d_out, int out_size, void* d_ws, size_t ws_size,
                              hipStream_t stream) {
  (void)in_sizes; (void)n_in; (void)out_size;
  const float* x    = (const float*)d_in[0];
  const float* Wg_s = (const float*)d_in[1];
  const float* Wu_s = (const float*)d_in[2];
  const float* Wd_s = (const float*)d_in[3];
  const float* Wg   = (const float*)d_in[4];
  const float* Wu   = (const float*)d_in[5];
  const float* Wd   = (const float*)d_in[6];
  const float* Wr   = (const float*)d_in[7];
  const float* rb   = (const float*)d_in[8];
  float* out = (float*)d_out;

  char* ws = (char*)d_ws;
  size_t off = 1024;               // counts: NEXP * CNT_STRIDE ints = 1 KB
  int* counts = (int*)ws;
  int* lists = (int*)(ws + off);  off += (size_t)NEXP * T_TOK * 4;
  float* cw = (float*)(ws + off); off += (size_t)T_TOK * NEXP * 4;
  int* td = (int*)(ws + off);     off += 2304;  // td_e | td_r0 | ntiles
  int* td_e = td;
  int* td_r0 = td + MAX_RT;
  int* ntiles = td + 2 * MAX_RT;

  const size_t WSH = (size_t)IDIM * HDIM;
  const size_t xc_elems = (size_t)T_TOK * HDIM;
  const size_t wc_elems = 3 * WSH + 3 * NEXP * WSH;   // 27*WSH
  const size_t fast_need = off + (xc_elems + wc_elems) * 2 + (size_t)2048 * IDIM * 2;
  const bool fast = ws_size >= fast_need;

  u16* xc = (u16*)(ws + off);
  u16* wgs_c = xc + (fast ? xc_elems : 0);
  u16* wus_c = wgs_c + WSH;
  u16* wds_c = wus_c + WSH;
  u16* wg_c = wds_c + WSH;
  u16* wu_c = wg_c + NEXP * WSH;
  u16* wd_c = wu_c + NEXP * WSH;

  size_t hoff = off + (fast ? (xc_elems + wc_elems) * 2 : 0);
  u16* hbuf = (u16*)(ws + hoff);

  size_t avail = (ws_size > hoff) ? (ws_size - hoff) : 0;
  // capacity in 128-row tiles (each tile: 128 * IDIM * 2 bytes of hbuf)
  long long ct = (long long)(avail / ((size_t)128 * IDIM * 2));
  int cap_tiles = (ct > MAX_RT) ? MAX_RT : (int)ct;
  if (cap_tiles < 1) cap_tiles = 1;
  int tpc = (cap_tiles < 132) ? cap_tiles : 132;   // 132 tiles -> 2 routed chunks

  init_counts<<<1, NEXP * CNT_STRIDE, 0, stream>>>(counts);
  router_kernel<<<T_TOK / TOK_PER_BLK, 256, 0, stream>>>(x, Wr, rb, cw, counts, lists);

  if (fast) {
    // batched f32->bf16 converts: x, shared weights (x3), routed weights (x3)
    {
      int n = (int)xc_elems;
      cvt_kernel<<<(n / 4 + 255) / 256, 256, 0, stream>>>(x, xc, n);
      int ns = (int)WSH;
      dim3 gs((ns / 4 + 255) / 256, 1, 3);
      cvt3_kernel<<<gs, 256, 0, stream>>>(Wg_s, Wu_s, Wd_s, wgs_c, wus_c, wds_c, ns);
      int nr = (int)(NEXP * WSH);
      dim3 gr((nr / 4 + 255) / 256, 1, 3);
      cvt3_kernel<<<gr, 256, 0, stream>>>(Wg, Wu, Wd, wg_c, wu_c, wd_c, nr);
    }
    build_tiles<<<1, 64, 0, stream>>>(counts, td_e, td_r0, ntiles);

    // ---- phase 1: shared expert, plain stores cover every output element ---
    for (int t0 = 0; t0 < SH_TILES; t0 += tpc) {
      int yt = (SH_TILES - t0 < tpc) ? (SH_TILES - t0) : tpc;
      gateup128f<<<dim3(IDIM / 128, yt), 256, 0, stream>>>(
          xc, wgs_c, wus_c, wg_c, wu_c, lists, counts, td_e, td_r0, ntiles,
          hbuf, t0, 0);
      down256f<<<dim3(HDIM / 256, yt), 256, 0, stream>>>(
          hbuf, wds_c, wd_c, lists, counts, td_e, td_r0, ntiles, cw, out, t0, 0);
    }
    // ---- phase 2: routed experts, atomic accumulate (stream-ordered after) -
    for (int t0 = 0; t0 < MAX_RT; t0 += tpc) {
      int yt = (MAX_RT - t0 < tpc) ? (MAX_RT - t0) : tpc;
      gateup128f<<<dim3(IDIM / 128, yt), 256, 0, stream>>>(
          xc, wgs_c, wus_c, wg_c, wu_c, lists, counts, td_e, td_r0, ntiles,
          hbuf, t0, 1);
      down256f<<<dim3(HDIM / 256, yt), 256, 0, stream>>>(
          hbuf, wds_c, wd_c, lists, counts, td_e, td_r0, ntiles, cw, out, t0, 1);
    }
  } else {
    // fallback: f32-source 128^2 path, serialized per-expert RMW
    int fcap = tpc * 128;
    int nchunks = (T_TOK + fcap - 1) / fcap;
    dim3 blk(256);
    dim3 gA(IDIM / 128, fcap / 128);
    dim3 gB(HDIM / 128, fcap / 128);
    for (int c = 0; c < nchunks; ++c) {
      int c0 = c * fcap;
      moe_gateup_k<<<gA, blk, 0, stream>>>(x, Wg_s, Wu_s, nullptr, nullptr, hbuf, c0);
      moe_down_k<<<gB, blk, 0, stream>>>(hbuf, Wd_s, nullptr, nullptr, cw, -1, out, c0);
    }
    for (int e = 0; e < NEXP; ++e) {
      const int* lst = lists + (size_t)e * T_TOK;
      const int* cptr = counts + (size_t)e * CNT_STRIDE;
      for (int c = 0; c < nchunks; ++c) {
        int c0 = c * fcap;
        moe_gateup_k<<<gA, blk, 0, stream>>>(x, Wg + (size_t)e * WSH, Wu + (size_t)e * WSH,
                                             lst, cptr, hbuf, c0);
        moe_down_k<<<gB, blk, 0, stream>>>(hbuf, Wd + (size_t)e * WSH,
                                           lst, cptr, cw, e, out, c0);
      }
    }
  }
}